// Round 8
// baseline (1254.323 us; speedup 1.0000x reference)
//
#include <hip/hip_runtime.h>
#include <math.h>

#define BATCH 512
#define NG 16
#define GSZ 32
#define H 128
#define E 64
#define PRE 512
#define BOT 1024
#define MLPD 1024
#define SEQ 12
#define AK 1152   // Abf row length = H + BOT

typedef __attribute__((ext_vector_type(8))) short bf16x8;
typedef __attribute__((ext_vector_type(4))) float f32x4;

__device__ __forceinline__ unsigned short f2bf(float f) {
    unsigned u = __float_as_uint(f);
    u += 0x7FFF + ((u >> 16) & 1);   // round-to-nearest-even
    return (unsigned short)(u >> 16);
}
__device__ __forceinline__ float bf2f(unsigned short s) {
    return __uint_as_float(((unsigned)s) << 16);
}

#define GLB(p) ((const __attribute__((address_space(1))) unsigned int*)(p))
#define LDS(p) ((__attribute__((address_space(3))) unsigned int*)(p))

// ---------------------------------------------------------------- one-shot prep
#define N0 (BOT * PRE)        /* W2b   */
#define N1 (MLPD * AK)        /* Wm1b  */
#define N2 (H * MLPD)         /* Wm2b  */
#define N3 (PRE * H)          /* W1hb  */
#define N4 (PRE)              /* wc    */
#define N5 (BATCH * H)        /* h/c   */
#define N6 (BATCH * 2)        /* pos   */
#define PREP_TOT (N0 + N1 + N2 + N3 + N4 + N5 + N6 + 1)

__global__ void prep_kernel(
    const float* __restrict__ W2, const float* __restrict__ Wm1,
    const float* __restrict__ Wm2, const float* __restrict__ W1,
    const float* __restrict__ Wp, const float* __restrict__ bp, const float* __restrict__ b1,
    const float* __restrict__ hh, const float* __restrict__ ch, const float* __restrict__ last_pos,
    unsigned short* __restrict__ W2b, unsigned short* __restrict__ Wm1b,
    unsigned short* __restrict__ Wm2b, unsigned short* __restrict__ W1hb,
    float* __restrict__ Wcx, float* __restrict__ Wcy, float* __restrict__ biash,
    float* __restrict__ hbuf, float* __restrict__ cbuf, float* __restrict__ pos,
    float* __restrict__ loss)
{
    long idx = (long)blockIdx.x * 256 + threadIdx.x;
    if (idx < N0) { W2b[idx] = f2bf(W2[idx]); return; }
    idx -= N0;
    if (idx < N1) { Wm1b[idx] = f2bf(Wm1[idx]); return; }
    idx -= N1;
    if (idx < N2) { Wm2b[idx] = f2bf(Wm2[idx]); return; }
    idx -= N2;
    if (idx < N3) { int r = (int)(idx >> 7), c = (int)(idx & 127);
                    W1hb[idx] = f2bf(W1[r * 192 + E + c]); return; }
    idx -= N3;
    if (idx < N4) {
        int p = (int)idx;
        float sx = 0.f, sy = 0.f, sb = 0.f;
#pragma unroll 8
        for (int e = 0; e < E; ++e) {
            float w = W1[p * 192 + e];
            sx += w * Wp[e * 2 + 0];
            sy += w * Wp[e * 2 + 1];
            sb += w * bp[e];
        }
        Wcx[p] = sx; Wcy[p] = sy; biash[p] = b1[p] + sb;
        return;
    }
    idx -= N4;
    if (idx < N5) { hbuf[idx] = hh[idx]; cbuf[idx] = ch[idx]; return; }
    idx -= N5;
    if (idx < N6) { pos[idx] = last_pos[idx]; return; }
    idx -= N6;
    if (idx == 0) *loss = 0.0f;
}

// ---------------------------------------------------------------- fused step head:
// (t>0) h_prev = relu(dh @ Wm2^T + bm2)  [M2 matvec, row-local]
// LSTM cell -> h ; Abf[b][0:128] = bf16(h) ; Hpart[b][:] = h @ W1h^T + biash ; rel_pos/traj/loss
__global__ __launch_bounds__(256) void lstm_step(
    int t,
    const float* __restrict__ relin, const float* __restrict__ gt,
    const float* __restrict__ Wse, const float* __restrict__ bse,
    const float* __restrict__ Wih, const float* __restrict__ Whh,
    const float* __restrict__ bih, const float* __restrict__ bhh,
    const float* __restrict__ Wpos, const float* __restrict__ bpos,
    const unsigned short* __restrict__ Wm2b, const float* __restrict__ bm2,
    const unsigned short* __restrict__ W1hb, const float* __restrict__ biash,
    const float* __restrict__ dhf, const float* __restrict__ hbuf,
    float* __restrict__ cbuf, unsigned short* __restrict__ Abf,
    float* __restrict__ Hpartf,
    float* __restrict__ pos, float* __restrict__ traj, float* __restrict__ loss)
{
    int b = blockIdx.x, tid = threadIdx.x;
    __shared__ __align__(16) float xe[E];
    __shared__ __align__(16) float hp[H];
    __shared__ __align__(16) float hn[H];
    __shared__ __align__(16) float dhs[MLPD];

    if (tid < E) {
        float rx = relin[b * 2 + 0], ry = relin[b * 2 + 1];
        xe[tid] = bse[tid] + Wse[tid * 2 + 0] * rx + Wse[tid * 2 + 1] * ry;
    }
    if (t == 0) {
        if (tid < H) hp[tid] = hbuf[b * H + tid];
    } else {
        // stage dh row (fp32, 4KB): 256 threads x float4
        ((float4*)dhs)[tid] = ((const float4*)&dhf[(size_t)b * MLPD])[tid];
    }
    __syncthreads();
    if (t > 0) {
        // h_prev = relu(dh . Wm2^T + bm2), 2 threads per output, K split 512/512
        int o = tid >> 1, half = tid & 1;
        const uint4* w4 = (const uint4*)&Wm2b[(size_t)o * MLPD + half * 512];
        const float4* d4 = (const float4*)&dhs[half * 512];
        float acc = 0.f;
#pragma unroll 16
        for (int k8 = 0; k8 < 64; ++k8) {
            uint4 wv = w4[k8];
            float4 da = d4[k8 * 2], db = d4[k8 * 2 + 1];
            acc += bf2f((unsigned short)(wv.x & 0xffff)) * da.x
                 + bf2f((unsigned short)(wv.x >> 16))    * da.y
                 + bf2f((unsigned short)(wv.y & 0xffff)) * da.z
                 + bf2f((unsigned short)(wv.y >> 16))    * da.w
                 + bf2f((unsigned short)(wv.z & 0xffff)) * db.x
                 + bf2f((unsigned short)(wv.z >> 16))    * db.y
                 + bf2f((unsigned short)(wv.w & 0xffff)) * db.z
                 + bf2f((unsigned short)(wv.w >> 16))    * db.w;
        }
        acc += __shfl_xor(acc, 1);
        if (half == 0) hp[o] = fmaxf(acc + bm2[o], 0.f);
        __syncthreads();
    }

    if (tid < H) {
        float g4[4];
        const float4* xev = (const float4*)xe;
        const float4* hpv = (const float4*)hp;
#pragma unroll
        for (int q = 0; q < 4; q++) {
            int row = q * H + tid;
            float acc = bih[row] + bhh[row];
            const float4* wi = (const float4*)(Wih + row * E);
#pragma unroll 4
            for (int k = 0; k < E / 4; k++) {
                float4 w = wi[k], x = xev[k];
                acc += w.x * x.x + w.y * x.y + w.z * x.z + w.w * x.w;
            }
            const float4* wh = (const float4*)(Whh + row * H);
#pragma unroll 4
            for (int k = 0; k < H / 4; k++) {
                float4 w = wh[k], x = hpv[k];
                acc += w.x * x.x + w.y * x.y + w.z * x.z + w.w * x.w;
            }
            g4[q] = acc;
        }
        float ig = 1.0f / (1.0f + expf(-g4[0]));
        float fg = 1.0f / (1.0f + expf(-g4[1]));
        float gg = tanhf(g4[2]);
        float og = 1.0f / (1.0f + expf(-g4[3]));
        float c = fg * cbuf[b * H + tid] + ig * gg;
        cbuf[b * H + tid] = c;
        float h = og * tanhf(c);
        Abf[(size_t)b * AK + tid] = f2bf(h);
        hn[tid] = h;
    }
    __syncthreads();

    // Hpart[b][:] = hn . W1h^T + biash   (2 outputs/thread, bf16 weights) — dead at last step
    if (t < SEQ - 1) {
#pragma unroll
        for (int half = 0; half < 2; ++half) {
            int pr = tid + half * 256;
            const uint4* w4 = (const uint4*)&W1hb[(size_t)pr * H];
            float acc = 0.f;
#pragma unroll
            for (int k8 = 0; k8 < 16; ++k8) {
                uint4 wv = w4[k8];
                const float* h8 = &hn[k8 * 8];
                acc += bf2f((unsigned short)(wv.x & 0xffff)) * h8[0]
                     + bf2f((unsigned short)(wv.x >> 16))    * h8[1]
                     + bf2f((unsigned short)(wv.y & 0xffff)) * h8[2]
                     + bf2f((unsigned short)(wv.y >> 16))    * h8[3]
                     + bf2f((unsigned short)(wv.z & 0xffff)) * h8[4]
                     + bf2f((unsigned short)(wv.z >> 16))    * h8[5]
                     + bf2f((unsigned short)(wv.w & 0xffff)) * h8[6]
                     + bf2f((unsigned short)(wv.w >> 16))    * h8[7];
            }
            Hpartf[(size_t)b * PRE + pr] = acc + biash[pr];
        }
    }

    if (tid < 2) {
        float acc = bpos[tid];
        const float* wr = Wpos + tid * H;
        for (int k = 0; k < H; k++) acc += wr[k] * hn[k];
        float lp = pos[b * 2 + tid];
        pos[b * 2 + tid] = acc + lp;
        traj[b * 2 + tid] = acc;
        float d = acc - gt[b * 2 + tid];
        atomicAdd(loss, d * d * (1.0f / 1024.0f));
    }
}

// ---------------------------------------------------------------- M1: dh(fp32) = relu([h|pool] @ Wm1^T + bm1)
// 64x32 tiles, waves 2x2 (NT=1)
__global__ __launch_bounds__(256) void m1_gemm(
    const unsigned short* __restrict__ A,
    const unsigned short* __restrict__ B,
    const float* __restrict__ bias,
    float* __restrict__ Cf)
{
    constexpr int BM = 64, BN = 32, MT = 2, NT = 1;
    const int K = AK, lda = AK, ldb = AK, ldc = MLPD;
    __shared__ __align__(16) unsigned short As[BM * 64];
    __shared__ __align__(16) unsigned short Bs[BN * 64];
    int tid = threadIdx.x;
    int lane = tid & 63, w = tid >> 6, wm = w >> 1, wn = w & 1;
    int quad = lane >> 4, l16 = lane & 15;
    int m0 = blockIdx.y * BM, n0 = blockIdx.x * BN;

    f32x4 acc[MT][NT];
#pragma unroll
    for (int mt = 0; mt < MT; ++mt) acc[mt][0] = (f32x4)0.f;

    for (int k0 = 0; k0 < K; k0 += 64) {
#pragma unroll
        for (int it = 0; it < BM / 32; ++it) {
            int c = it * 256 + tid;
            __builtin_amdgcn_global_load_lds(
                GLB(A + (size_t)(m0 + (c >> 3)) * lda + k0 + (c & 7) * 8),
                LDS(&As[c * 8]), 16, 0, 0);
        }
        {
            int c = tid;
            __builtin_amdgcn_global_load_lds(
                GLB(B + (size_t)(n0 + (c >> 3)) * ldb + k0 + (c & 7) * 8),
                LDS(&Bs[c * 8]), 16, 0, 0);
        }
        __syncthreads();
#pragma unroll
        for (int ks = 0; ks < 2; ++ks) {
            bf16x8 af[MT], bfr;
#pragma unroll
            for (int mt = 0; mt < MT; ++mt)
                af[mt] = *(const bf16x8*)&As[(wm * 32 + mt * 16 + l16) * 64 + ks * 32 + quad * 8];
            bfr = *(const bf16x8*)&Bs[(wn * 16 + l16) * 64 + ks * 32 + quad * 8];
#pragma unroll
            for (int mt = 0; mt < MT; ++mt)
                acc[mt][0] = __builtin_amdgcn_mfma_f32_16x16x32_bf16(af[mt], bfr, acc[mt][0], 0, 0, 0);
        }
        __syncthreads();
    }

#pragma unroll
    for (int mt = 0; mt < MT; ++mt) {
        int rbase = m0 + wm * 32 + mt * 16 + quad * 4;
        int col = n0 + wn * 16 + l16;
        float bv = bias[col];
#pragma unroll
        for (int r = 0; r < 4; ++r) {
            float v = acc[mt][0][r] + bv;
            Cf[(size_t)(rbase + r) * ldc + col] = fmaxf(v, 0.f);
        }
    }
}

// ---------------------------------------------------------------- pool GEMM2, fused x1 A-tile build (R5-proven)
__global__ __launch_bounds__(256) void pool_gemm(
    const float* __restrict__ Hpartf, const float* __restrict__ pos,
    const float* __restrict__ Wcx, const float* __restrict__ Wcy,
    const unsigned short* __restrict__ W2b,
    const float* __restrict__ b2, unsigned short* __restrict__ Abf)
{
    constexpr int BM = 128, BN = 128, MT = 4, NT = 4;
    constexpr int LDA = 72;
    __shared__ __align__(16) unsigned short As[BM * LDA];
    __shared__ __align__(16) unsigned short Bs[BN * 64];
    __shared__ float red[4 * 128];
    __shared__ float px[GSZ], py[GSZ];
    int tid = threadIdx.x;
    int lane = tid & 63, w = tid >> 6, wm = w >> 1, wn = w & 1;
    int quad = lane >> 4, l16 = lane & 15;
    int bid = blockIdx.x;
    int m_tile = ((bid & 7) << 4) | (bid >> 6);
    int n_tile = (bid >> 3) & 7;
    int g = m_tile >> 3, iq = m_tile & 7;
    int n0 = n_tile * BN;

    if (tid < GSZ) { px[tid] = pos[(g * GSZ + tid) * 2]; py[tid] = pos[(g * GSZ + tid) * 2 + 1]; }

    f32x4 acc[MT][NT];
#pragma unroll
    for (int mt = 0; mt < MT; ++mt)
#pragma unroll
        for (int nt = 0; nt < NT; ++nt) acc[mt][nt] = (f32x4)0.f;

    int jA = tid >> 3, k8 = (tid & 7) * 8;
    __syncthreads();
    float pjx = px[jA], pjy = py[jA];

    for (int k0 = 0; k0 < PRE; k0 += 64) {
#pragma unroll
        for (int it = 0; it < 4; ++it) {
            int c = it * 256 + tid;
            __builtin_amdgcn_global_load_lds(
                GLB(W2b + (size_t)(n0 + (c >> 3)) * PRE + k0 + (c & 7) * 8),
                LDS(&Bs[c * 8]), 16, 0, 0);
        }
        {
            const float4* hp4 = (const float4*)&Hpartf[(size_t)(g * GSZ + jA) * PRE + k0 + k8];
            float4 ha = hp4[0], hb = hp4[1];
            float4 wxa = *(const float4*)&Wcx[k0 + k8], wxb = *(const float4*)&Wcx[k0 + k8 + 4];
            float4 wya = *(const float4*)&Wcy[k0 + k8], wyb = *(const float4*)&Wcy[k0 + k8 + 4];
#pragma unroll
            for (int u = 0; u < 4; ++u) {
                int i = iq * 4 + u;
                float rx = pjx - px[i], ry = pjy - py[i];
                union { ushort s[8]; uint4 v; } o;
                o.s[0] = f2bf(fmaxf(ha.x + rx * wxa.x + ry * wya.x, 0.f));
                o.s[1] = f2bf(fmaxf(ha.y + rx * wxa.y + ry * wya.y, 0.f));
                o.s[2] = f2bf(fmaxf(ha.z + rx * wxa.z + ry * wya.z, 0.f));
                o.s[3] = f2bf(fmaxf(ha.w + rx * wxa.w + ry * wya.w, 0.f));
                o.s[4] = f2bf(fmaxf(hb.x + rx * wxb.x + ry * wyb.x, 0.f));
                o.s[5] = f2bf(fmaxf(hb.y + rx * wxb.y + ry * wyb.y, 0.f));
                o.s[6] = f2bf(fmaxf(hb.z + rx * wxb.z + ry * wyb.z, 0.f));
                o.s[7] = f2bf(fmaxf(hb.w + rx * wxb.w + ry * wyb.w, 0.f));
                *(uint4*)&As[(u * GSZ + jA) * LDA + k8] = o.v;
            }
        }
        __syncthreads();
#pragma unroll
        for (int ks = 0; ks < 2; ++ks) {
            bf16x8 af[MT], bfr[NT];
#pragma unroll
            for (int mt = 0; mt < MT; ++mt)
                af[mt] = *(const bf16x8*)&As[(wm * 64 + mt * 16 + l16) * LDA + ks * 32 + quad * 8];
#pragma unroll
            for (int nt = 0; nt < NT; ++nt)
                bfr[nt] = *(const bf16x8*)&Bs[(wn * 64 + nt * 16 + l16) * 64 + ks * 32 + quad * 8];
#pragma unroll
            for (int mt = 0; mt < MT; ++mt)
#pragma unroll
                for (int nt = 0; nt < NT; ++nt)
                    acc[mt][nt] = __builtin_amdgcn_mfma_f32_16x16x32_bf16(af[mt], bfr[nt], acc[mt][nt], 0, 0, 0);
        }
        __syncthreads();
    }

#pragma unroll
    for (int nt = 0; nt < NT; ++nt) {
        float u0 = -1e30f, u1 = -1e30f;
#pragma unroll
        for (int r = 0; r < 4; ++r) {
            u0 = fmaxf(u0, fmaxf(acc[0][nt][r], acc[1][nt][r]));
            u1 = fmaxf(u1, fmaxf(acc[2][nt][r], acc[3][nt][r]));
        }
        u0 = fmaxf(u0, __shfl_xor(u0, 16)); u0 = fmaxf(u0, __shfl_xor(u0, 32));
        u1 = fmaxf(u1, __shfl_xor(u1, 16)); u1 = fmaxf(u1, __shfl_xor(u1, 32));
        if (lane < 16) {
            red[(wm * 2 + 0) * 128 + wn * 64 + nt * 16 + lane] = u0;
            red[(wm * 2 + 1) * 128 + wn * 64 + nt * 16 + lane] = u1;
        }
    }
    __syncthreads();
    for (int e = tid; e < 512; e += 256) {
        int u = e >> 7, cc = e & 127;
        int gu = m_tile * 4 + u;
        float v = fmaxf(red[e] + b2[n0 + cc], 0.f);
        Abf[(size_t)gu * AK + H + n0 + cc] = f2bf(v);
    }
}

// ---------------------------------------------------------------- launch
extern "C" void kernel_launch(void* const* d_in, const int* in_sizes, int n_in,
                              void* d_out, int out_size, void* d_ws, size_t ws_size,
                              hipStream_t stream)
{
    const float* last_pos     = (const float*)d_in[0];
    const float* last_pos_rel = (const float*)d_in[1];
    const float* hh           = (const float*)d_in[2];
    const float* ch           = (const float*)d_in[3];
    const float* ptr_rel      = (const float*)d_in[4];
    const float* Wih  = (const float*)d_in[6];
    const float* Whh  = (const float*)d_in[7];
    const float* bih  = (const float*)d_in[8];
    const float* bhh  = (const float*)d_in[9];
    const float* Wse  = (const float*)d_in[10];
    const float* bse  = (const float*)d_in[11];
    const float* Wpos = (const float*)d_in[12];
    const float* bpos = (const float*)d_in[13];
    const float* Wp   = (const float*)d_in[14];
    const float* bp   = (const float*)d_in[15];
    const float* W1   = (const float*)d_in[16];
    const float* b1   = (const float*)d_in[17];
    const float* W2   = (const float*)d_in[18];
    const float* b2   = (const float*)d_in[19];
    const float* Wm1  = (const float*)d_in[20];
    const float* bm1  = (const float*)d_in[21];
    const float* Wm2  = (const float*)d_in[22];
    const float* bm2  = (const float*)d_in[23];

    float* ws     = (float*)d_ws;
    float* hbuf   = ws;                       // 65536
    float* cbuf   = hbuf + BATCH * H;         // 65536
    float* pos    = cbuf + BATCH * H;         // 1024
    float* Hpartf = pos + 1024;               // 262144
    float* dhf    = Hpartf + BATCH * PRE;     // 524288 (fp32 dh)
    float* Wcx    = dhf + (size_t)BATCH * MLPD;
    float* Wcy    = Wcx + PRE;
    float* biash  = Wcy + PRE;
    unsigned short* ub    = (unsigned short*)(biash + PRE);
    unsigned short* Abf   = ub;                         // 512*1152
    unsigned short* W2b   = Abf + (size_t)BATCH * AK;
    unsigned short* Wm1b  = W2b + (size_t)BOT * PRE;
    unsigned short* Wm2b  = Wm1b + (size_t)MLPD * AK;
    unsigned short* W1hb  = Wm2b + (size_t)H * MLPD;

    float* out  = (float*)d_out;
    float* loss = out + SEQ * BATCH * 2;

    prep_kernel<<<(PREP_TOT + 255) / 256, 256, 0, stream>>>(
        W2, Wm1, Wm2, W1, Wp, bp, b1, hh, ch, last_pos,
        W2b, Wm1b, Wm2b, W1hb, Wcx, Wcy, biash, hbuf, cbuf, pos, loss);

    for (int t = 0; t < SEQ; t++) {
        const float* relin = (t == 0) ? last_pos_rel : (ptr_rel + (t - 1) * BATCH * 2);
        const float* gt = ptr_rel + t * BATCH * 2;
        lstm_step<<<BATCH, 256, 0, stream>>>(t, relin, gt, Wse, bse, Wih, Whh, bih, bhh,
                                             Wpos, bpos, Wm2b, bm2, W1hb, biash,
                                             dhf, hbuf, cbuf, Abf, Hpartf, pos,
                                             out + t * BATCH * 2, loss);
        if (t == SEQ - 1) break;   // h after last step is dead
        pool_gemm<<<1024, 256, 0, stream>>>(Hpartf, pos, Wcx, Wcy, W2b, b2, Abf);
        m1_gemm<<<dim3(MLPD / 32, BATCH / 64), 256, 0, stream>>>(Abf, Wm1b, bm1, dhf);
    }
}